// Round 3
// baseline (222.559 us; speedup 1.0000x reference)
//
#include <hip/hip_runtime.h>
#include <climits>

// Problem constants
#define B_N 64
#define C_N 256
#define M_N 1024
#define P_N 512
#define D_N 16
#define WPP 8   // 8 u64 words per 512-bit pattern

// Grid = 512: block bid handles neuron c = bid>>1, entry half = bid&1
// (512 entries). Packs sign bits into LDS (32 KB), computes partial
// Hamming-argmin keys for all 64 batch rows, writes keys to d_ws.
// Kernel 2 min-reduces the two halves and gathers value_logits > 0.
//
// Bit-order permutation (identical for patterns and query bits, so Hamming
// distance is preserved): word j of an entry packs positions
//   p_local = (j>>2)*256 + 4*lane + (j&3)

#define PLOAD(A0, A1, A2, A3, i)                                   \
  {                                                                \
    const float4* s_ = (const float4*)(pc + (size_t)(i) * 1024);   \
    A0 = s_[lane];                                                 \
    A1 = s_[64 + lane];                                            \
    A2 = s_[128 + lane];                                           \
    A3 = s_[192 + lane];                                           \
  }

#define PPROC(A0, A1, A2, A3, i)                                              \
  {                                                                           \
    unsigned long long held_ = 0, bal_;                                       \
    bal_ = __ballot(A0.x > 0.0f); if (lane == 0)  held_ = bal_;               \
    bal_ = __ballot(A0.y > 0.0f); if (lane == 1)  held_ = bal_;               \
    bal_ = __ballot(A0.z > 0.0f); if (lane == 2)  held_ = bal_;               \
    bal_ = __ballot(A0.w > 0.0f); if (lane == 3)  held_ = bal_;               \
    bal_ = __ballot(A1.x > 0.0f); if (lane == 4)  held_ = bal_;               \
    bal_ = __ballot(A1.y > 0.0f); if (lane == 5)  held_ = bal_;               \
    bal_ = __ballot(A1.z > 0.0f); if (lane == 6)  held_ = bal_;               \
    bal_ = __ballot(A1.w > 0.0f); if (lane == 7)  held_ = bal_;               \
    bal_ = __ballot(A2.x > 0.0f); if (lane == 8)  held_ = bal_;               \
    bal_ = __ballot(A2.y > 0.0f); if (lane == 9)  held_ = bal_;               \
    bal_ = __ballot(A2.z > 0.0f); if (lane == 10) held_ = bal_;               \
    bal_ = __ballot(A2.w > 0.0f); if (lane == 11) held_ = bal_;               \
    bal_ = __ballot(A3.x > 0.0f); if (lane == 12) held_ = bal_;               \
    bal_ = __ballot(A3.y > 0.0f); if (lane == 13) held_ = bal_;               \
    bal_ = __ballot(A3.z > 0.0f); if (lane == 14) held_ = bal_;               \
    bal_ = __ballot(A3.w > 0.0f); if (lane == 15) held_ = bal_;               \
    if (lane < 16) {                                                          \
      const int W_ = wid * 256 + (i) * 16 + lane;                             \
      const int m_ = W_ >> 3;                                                 \
      const int j_ = W_ & 7;                                                  \
      pat_lds[((j_ >> 1) << 10) + m_ * 2 + (j_ & 1)] = held_;                 \
    }                                                                         \
  }

__global__ __launch_bounds__(1024) void vgram_argmin(
    const float* __restrict__ bits,   // (B, C, P)
    const float* __restrict__ plog,   // (C, M, P)
    int* __restrict__ ws_keys)        // (C, B, 2)
{
    // pattern LDS: plane k (k=0..3) holds words j=2k,2k+1:
    //   pat_lds[k*1024 + mloc*2 + (j&1)], mloc in [0,512)
    __shared__ __align__(16) unsigned long long pat_lds[4 * 1024];  // 32 KB
    __shared__ unsigned long long bits_lds[B_N * WPP];              // 4 KB

    const int c    = blockIdx.x >> 1;
    const int half = blockIdx.x & 1;
    const int tid  = threadIdx.x;
    const int lane = tid & 63;
    const int wid  = tid >> 6;   // 0..15

    // ---------------- Phase A: pack query bits (same permutation) ----------
    {
        const int b0 = wid * 4;
        #pragma unroll
        for (int bb = 0; bb < 4; ++bb) {
            const int b = b0 + bb;
            const float4* src = (const float4*)(bits + ((size_t)b * C_N + c) * P_N);
            const float4 f0 = src[lane];        // q=0: positions 4*lane+k
            const float4 f1 = src[64 + lane];   // q=1: positions 256+4*lane+k
            unsigned long long held = 0, bal;
            bal = __ballot(f0.x > 0.0f); if (lane == 0) held = bal;
            bal = __ballot(f0.y > 0.0f); if (lane == 1) held = bal;
            bal = __ballot(f0.z > 0.0f); if (lane == 2) held = bal;
            bal = __ballot(f0.w > 0.0f); if (lane == 3) held = bal;
            bal = __ballot(f1.x > 0.0f); if (lane == 4) held = bal;
            bal = __ballot(f1.y > 0.0f); if (lane == 5) held = bal;
            bal = __ballot(f1.z > 0.0f); if (lane == 6) held = bal;
            bal = __ballot(f1.w > 0.0f); if (lane == 7) held = bal;
            if (lane < 8) bits_lds[b * WPP + lane] = held;
        }
    }

    // ---------------- Phase B: pack patterns, double-buffered --------------
    // Block covers entries [half*512, half*512+512) = 4096 u64 words.
    // Wave wid owns words [wid*256, wid*256+256) = floats [wid*16384, +16384).
    const float* pc = plog + (size_t)c * (M_N * P_N)
                    + (size_t)half * (512 * P_N) + (size_t)wid * 16384;

    {
        float4 a0, a1, a2, a3, b0, b1, b2, b3;
        PLOAD(a0, a1, a2, a3, 0);
        #pragma unroll 1
        for (int i = 0; i < 14; i += 2) {
            PLOAD(b0, b1, b2, b3, i + 1);
            PPROC(a0, a1, a2, a3, i);
            PLOAD(a0, a1, a2, a3, i + 2);
            PPROC(b0, b1, b2, b3, i + 1);
        }
        PLOAD(b0, b1, b2, b3, 15);
        PPROC(a0, a1, a2, a3, 14);
        PPROC(b0, b1, b2, b3, 15);
    }
    __syncthreads();

    // ---------------- Phase C: distances + partial argmin ------------------
    const int bbase = wid * 4;   // 16 waves x 4 = 64 batch rows

    unsigned long long bw[4][WPP];
    #pragma unroll
    for (int bb = 0; bb < 4; ++bb)
        #pragma unroll
        for (int j = 0; j < WPP; ++j)
            bw[bb][j] = bits_lds[(bbase + bb) * WPP + j];

    int key[4] = {INT_MAX, INT_MAX, INT_MAX, INT_MAX};

    for (int mm = 0; mm < 8; ++mm) {
        const int m = mm * 64 + lane;          // local entry 0..511
        unsigned long long pw[WPP];
        #pragma unroll
        for (int k = 0; k < 4; ++k) {
            const ulonglong2 v =
                *reinterpret_cast<const ulonglong2*>(&pat_lds[(k << 10) + m * 2]);
            pw[2 * k]     = v.x;
            pw[2 * k + 1] = v.y;
        }
        const int gm = (half << 9) | m;        // global entry index
        #pragma unroll
        for (int bb = 0; bb < 4; ++bb) {
            int d = 0;
            #pragma unroll
            for (int j = 0; j < WPP; ++j)
                d += __popcll(pw[j] ^ bw[bb][j]);
            const int k2 = (d << 10) | gm;
            key[bb] = min(key[bb], k2);
        }
    }

    #pragma unroll
    for (int bb = 0; bb < 4; ++bb) {
        int k2 = key[bb];
        #pragma unroll
        for (int off = 32; off; off >>= 1)
            k2 = min(k2, __shfl_xor(k2, off));
        if (lane == 0)
            ws_keys[((c * B_N) + bbase + bb) * 2 + half] = k2;
    }
}

// Grid = 256 (one block per c), 1024 threads: tid = b*16 + d.
__global__ __launch_bounds__(1024) void vgram_gather(
    const int* __restrict__ ws_keys,  // (C, B, 2)
    const float* __restrict__ vlog,   // (C, M, D)
    float* __restrict__ out)          // (B, C, D)
{
    const int c = blockIdx.x;
    const int b = threadIdx.x >> 4;
    const int d = threadIdx.x & 15;
    const int k0 = ws_keys[((c * B_N) + b) * 2 + 0];
    const int k1 = ws_keys[((c * B_N) + b) * 2 + 1];
    const int idx = min(k0, k1) & 1023;
    const float v = vlog[((size_t)c * M_N + idx) * D_N + d];
    out[((size_t)b * C_N + c) * D_N + d] = (v > 0.0f) ? 1.0f : 0.0f;
}

extern "C" void kernel_launch(void* const* d_in, const int* in_sizes, int n_in,
                              void* d_out, int out_size, void* d_ws, size_t ws_size,
                              hipStream_t stream) {
    const float* bits = (const float*)d_in[0];   // (64, 256, 512)
    const float* plog = (const float*)d_in[1];   // (256, 1024, 512)
    const float* vlog = (const float*)d_in[2];   // (256, 1024, 16)
    float* out = (float*)d_out;                  // (64, 256, 16)
    int* ws_keys = (int*)d_ws;                   // 256*64*2 ints = 128 KB

    vgram_argmin<<<C_N * 2, 1024, 0, stream>>>(bits, plog, ws_keys);
    vgram_gather<<<C_N, 1024, 0, stream>>>(ws_keys, vlog, out);
}

// Round 4
// 122.173 us; speedup vs baseline: 1.8217x; 1.8217x over previous
//
#include <hip/hip_runtime.h>
#include <climits>

// Problem constants
#define B_N 64
#define C_N 256
#define M_N 1024
#define P_N 512
#define D_N 16
#define WPP 8   // 8 u64 words per 512-bit pattern

// Single kernel, grid=256 (one block per neuron c), 1024 threads = 16 waves,
// 1 block/CU (R2-proven structure). Change vs R2: 4-deep register pipeline
// for pattern staging (16 KB/wave in flight instead of 8 KB) and phase-A
// loads issued before the pattern prologue.
//
// Bit-order permutation (identical for patterns and query bits, so Hamming
// distance is preserved): word j of an entry packs positions
//   p_local = (j>>2)*256 + 4*lane + (j&3)

#define PLOAD(A0, A1, A2, A3, i)                                   \
  {                                                                \
    const float4* s_ = (const float4*)(pc + (size_t)(i) * 1024);   \
    A0 = s_[lane];                                                 \
    A1 = s_[64 + lane];                                            \
    A2 = s_[128 + lane];                                           \
    A3 = s_[192 + lane];                                           \
  }

#define PPROC(A0, A1, A2, A3, i)                                              \
  {                                                                           \
    unsigned long long held_ = 0, bal_;                                       \
    bal_ = __ballot(A0.x > 0.0f); if (lane == 0)  held_ = bal_;               \
    bal_ = __ballot(A0.y > 0.0f); if (lane == 1)  held_ = bal_;               \
    bal_ = __ballot(A0.z > 0.0f); if (lane == 2)  held_ = bal_;               \
    bal_ = __ballot(A0.w > 0.0f); if (lane == 3)  held_ = bal_;               \
    bal_ = __ballot(A1.x > 0.0f); if (lane == 4)  held_ = bal_;               \
    bal_ = __ballot(A1.y > 0.0f); if (lane == 5)  held_ = bal_;               \
    bal_ = __ballot(A1.z > 0.0f); if (lane == 6)  held_ = bal_;               \
    bal_ = __ballot(A1.w > 0.0f); if (lane == 7)  held_ = bal_;               \
    bal_ = __ballot(A2.x > 0.0f); if (lane == 8)  held_ = bal_;               \
    bal_ = __ballot(A2.y > 0.0f); if (lane == 9)  held_ = bal_;               \
    bal_ = __ballot(A2.z > 0.0f); if (lane == 10) held_ = bal_;               \
    bal_ = __ballot(A2.w > 0.0f); if (lane == 11) held_ = bal_;               \
    bal_ = __ballot(A3.x > 0.0f); if (lane == 12) held_ = bal_;               \
    bal_ = __ballot(A3.y > 0.0f); if (lane == 13) held_ = bal_;               \
    bal_ = __ballot(A3.z > 0.0f); if (lane == 14) held_ = bal_;               \
    bal_ = __ballot(A3.w > 0.0f); if (lane == 15) held_ = bal_;               \
    if (lane < 16) {                                                          \
      const int W_ = wid * 512 + (i) * 16 + lane;                             \
      const int m_ = W_ >> 3;                                                 \
      const int j_ = W_ & 7;                                                  \
      pat_lds[((j_ >> 1) << 11) + m_ * 2 + (j_ & 1)] = held_;                 \
    }                                                                         \
  }

__global__ __launch_bounds__(1024) void vgram_kernel(
    const float* __restrict__ bits,   // (B, C, P)
    const float* __restrict__ plog,   // (C, M, P)
    const float* __restrict__ vlog,   // (C, M, D)
    float* __restrict__ out)          // (B, C, D)
{
    // pattern LDS: plane k (k=0..3) holds words j=2k,2k+1: [k*2048 + m*2 + (j&1)]
    __shared__ __align__(16) unsigned long long pat_lds[4 * 2048];  // 64 KB
    __shared__ unsigned long long bits_lds[B_N * WPP];              // 4 KB

    const int c    = blockIdx.x;
    const int tid  = threadIdx.x;
    const int lane = tid & 63;
    const int wid  = tid >> 6;   // 0..15

    // Wave wid owns pattern words [wid*512, +512) = floats [wid*32768, +32768).
    const float* pc = plog + (size_t)c * (M_N * P_N) + (size_t)wid * 32768;

    // ---------------- Phase A loads: query bits (issued first) -------------
    const int bbase = wid * 4;   // 16 waves x 4 = 64 batch rows
    float4 qa0, qa1, qb0, qb1, qc0, qc1, qd0, qd1;
    {
        const float4* s0 = (const float4*)(bits + ((size_t)(bbase + 0) * C_N + c) * P_N);
        const float4* s1 = (const float4*)(bits + ((size_t)(bbase + 1) * C_N + c) * P_N);
        const float4* s2 = (const float4*)(bits + ((size_t)(bbase + 2) * C_N + c) * P_N);
        const float4* s3 = (const float4*)(bits + ((size_t)(bbase + 3) * C_N + c) * P_N);
        qa0 = s0[lane]; qa1 = s0[64 + lane];
        qb0 = s1[lane]; qb1 = s1[64 + lane];
        qc0 = s2[lane]; qc1 = s2[64 + lane];
        qd0 = s3[lane]; qd1 = s3[64 + lane];
    }

    // ---------------- Pattern pipeline prologue: 4 batches in flight -------
    float4 a0, a1, a2, a3, b0, b1, b2, b3, c0, c1, c2, c3, d0, d1, d2, d3;
    PLOAD(a0, a1, a2, a3, 0);
    PLOAD(b0, b1, b2, b3, 1);
    PLOAD(c0, c1, c2, c3, 2);
    PLOAD(d0, d1, d2, d3, 3);

    // ---------------- Phase A ballots (pattern loads stay in flight) -------
    {
        #define QPROC(F0, F1, bb)                                          \
          {                                                                \
            unsigned long long held = 0, bal;                              \
            bal = __ballot(F0.x > 0.0f); if (lane == 0) held = bal;        \
            bal = __ballot(F0.y > 0.0f); if (lane == 1) held = bal;        \
            bal = __ballot(F0.z > 0.0f); if (lane == 2) held = bal;        \
            bal = __ballot(F0.w > 0.0f); if (lane == 3) held = bal;        \
            bal = __ballot(F1.x > 0.0f); if (lane == 4) held = bal;        \
            bal = __ballot(F1.y > 0.0f); if (lane == 5) held = bal;        \
            bal = __ballot(F1.z > 0.0f); if (lane == 6) held = bal;        \
            bal = __ballot(F1.w > 0.0f); if (lane == 7) held = bal;        \
            if (lane < 8) bits_lds[(bbase + (bb)) * WPP + lane] = held;    \
          }
        QPROC(qa0, qa1, 0);
        QPROC(qb0, qb1, 1);
        QPROC(qc0, qc1, 2);
        QPROC(qd0, qd1, 3);
        #undef QPROC
    }

    // ---------------- Phase B: 4-deep software pipeline --------------------
    #pragma unroll 1
    for (int i = 0; i < 28; i += 4) {
        PPROC(a0, a1, a2, a3, i);     PLOAD(a0, a1, a2, a3, i + 4);
        PPROC(b0, b1, b2, b3, i + 1); PLOAD(b0, b1, b2, b3, i + 5);
        PPROC(c0, c1, c2, c3, i + 2); PLOAD(c0, c1, c2, c3, i + 6);
        PPROC(d0, d1, d2, d3, i + 3); PLOAD(d0, d1, d2, d3, i + 7);
    }
    PPROC(a0, a1, a2, a3, 28);
    PPROC(b0, b1, b2, b3, 29);
    PPROC(c0, c1, c2, c3, 30);
    PPROC(d0, d1, d2, d3, 31);
    __syncthreads();

    // ---------------- Phase C: distances + argmin --------------------------
    unsigned long long bw[4][WPP];
    #pragma unroll
    for (int bb = 0; bb < 4; ++bb)
        #pragma unroll
        for (int j = 0; j < WPP; ++j)
            bw[bb][j] = bits_lds[(bbase + bb) * WPP + j];

    int key[4] = {INT_MAX, INT_MAX, INT_MAX, INT_MAX};

    for (int mm = 0; mm < 16; ++mm) {
        const int m = mm * 64 + lane;
        unsigned long long pw[WPP];
        #pragma unroll
        for (int k = 0; k < 4; ++k) {
            const ulonglong2 v =
                *reinterpret_cast<const ulonglong2*>(&pat_lds[(k << 11) + m * 2]);
            pw[2 * k]     = v.x;
            pw[2 * k + 1] = v.y;
        }
        #pragma unroll
        for (int bb = 0; bb < 4; ++bb) {
            int d = 0;
            #pragma unroll
            for (int j = 0; j < WPP; ++j)
                d += __popcll(pw[j] ^ bw[bb][j]);
            const int k2 = (d << 10) | m;
            key[bb] = min(key[bb], k2);
        }
    }

    // wave-wide min reduce per batch row; then gather+threshold values
    #pragma unroll
    for (int bb = 0; bb < 4; ++bb) {
        int k2 = key[bb];
        #pragma unroll
        for (int off = 32; off; off >>= 1)
            k2 = min(k2, __shfl_xor(k2, off));
        const int idx = k2 & 1023;
        const int b = bbase + bb;
        if (lane < D_N) {
            const float v = vlog[((size_t)c * M_N + idx) * D_N + lane];
            out[((size_t)b * C_N + c) * D_N + lane] = (v > 0.0f) ? 1.0f : 0.0f;
        }
    }
}

extern "C" void kernel_launch(void* const* d_in, const int* in_sizes, int n_in,
                              void* d_out, int out_size, void* d_ws, size_t ws_size,
                              hipStream_t stream) {
    const float* bits = (const float*)d_in[0];   // (64, 256, 512)
    const float* plog = (const float*)d_in[1];   // (256, 1024, 512)
    const float* vlog = (const float*)d_in[2];   // (256, 1024, 16)
    float* out = (float*)d_out;                  // (64, 256, 16)

    vgram_kernel<<<C_N, 1024, 0, stream>>>(bits, plog, vlog, out);
}

// Round 6
// 91.637 us; speedup vs baseline: 2.4287x; 1.3332x over previous
//
#include <hip/hip_runtime.h>
#include <climits>

// Problem constants
#define B_N 64
#define C_N 256
#define M_N 1024
#define P_N 512
#define D_N 16

typedef float f4 __attribute__((ext_vector_type(4)));  // nt-load-compatible

// Single kernel, grid=256 (one block per neuron c), 1024 threads = 16 waves.
//
// __ballot is wave-uniform (SGPR pair), so pattern words are consumed
// DIRECTLY as scalar operands -- no pattern LDS, no select chains, no
// staging/compute barrier. Each LANE holds one batch row's packed query
// (8 u64 = 16 VGPR, transposed once through LDS at start). Wave w owns
// entries [w*64, w*64+64); per 1024-float batch it ballots 16 words
// (2 entries) and immediately accumulates acc = min(acc, (d<<10)|m) per lane
// (lane = batch row). Exact jnp.argmin tie-break: key order = (d asc, m asc),
// waves own disjoint ascending m-ranges.
//
// Bit-order permutation (identical for patterns and queries, Hamming-
// invariant): word j of an entry packs positions (j>>2)*256 + 4*lane + (j&3).
//
// plog is a pure stream (zero reuse) -> nontemporal loads.

#define PLOAD(A0, A1, A2, A3, i)                                    \
  {                                                                 \
    const f4* s_ = (const f4*)(pc + (size_t)(i) * 1024);            \
    A0 = __builtin_nontemporal_load(s_ + lane);                     \
    A1 = __builtin_nontemporal_load(s_ + 64 + lane);                \
    A2 = __builtin_nontemporal_load(s_ + 128 + lane);               \
    A3 = __builtin_nontemporal_load(s_ + 192 + lane);               \
  }

// Ballot 16 words of batch i (entries wm+2i, wm+2i+1), optionally issue the
// next PLOAD, then accumulate both entries' distances into acc (per-lane b).
#define STEP(A0, A1, A2, A3, i, DO_LOAD)                                      \
  {                                                                           \
    const unsigned long long s0 = __ballot(A0.x > 0.0f);                      \
    const unsigned long long s1 = __ballot(A0.y > 0.0f);                      \
    const unsigned long long s2 = __ballot(A0.z > 0.0f);                      \
    const unsigned long long s3 = __ballot(A0.w > 0.0f);                      \
    const unsigned long long s4 = __ballot(A1.x > 0.0f);                      \
    const unsigned long long s5 = __ballot(A1.y > 0.0f);                      \
    const unsigned long long s6 = __ballot(A1.z > 0.0f);                      \
    const unsigned long long s7 = __ballot(A1.w > 0.0f);                      \
    const unsigned long long t0 = __ballot(A2.x > 0.0f);                      \
    const unsigned long long t1 = __ballot(A2.y > 0.0f);                      \
    const unsigned long long t2 = __ballot(A2.z > 0.0f);                      \
    const unsigned long long t3 = __ballot(A2.w > 0.0f);                      \
    const unsigned long long t4 = __ballot(A3.x > 0.0f);                      \
    const unsigned long long t5 = __ballot(A3.y > 0.0f);                      \
    const unsigned long long t6 = __ballot(A3.z > 0.0f);                      \
    const unsigned long long t7 = __ballot(A3.w > 0.0f);                      \
    if (DO_LOAD) { PLOAD(A0, A1, A2, A3, (i) + 4); }                          \
    {                                                                         \
      int d0 = __popcll(s0 ^ q0) + __popcll(s1 ^ q1) + __popcll(s2 ^ q2) +    \
               __popcll(s3 ^ q3) + __popcll(s4 ^ q4) + __popcll(s5 ^ q5) +    \
               __popcll(s6 ^ q6) + __popcll(s7 ^ q7);                         \
      acc = min(acc, (unsigned)((d0 << 10) | (wm + 2 * (i))));                \
      int d1 = __popcll(t0 ^ q0) + __popcll(t1 ^ q1) + __popcll(t2 ^ q2) +    \
               __popcll(t3 ^ q3) + __popcll(t4 ^ q4) + __popcll(t5 ^ q5) +    \
               __popcll(t6 ^ q6) + __popcll(t7 ^ q7);                         \
      acc = min(acc, (unsigned)((d1 << 10) | (wm + 2 * (i) + 1)));            \
    }                                                                         \
  }

__global__ __launch_bounds__(1024) void vgram_kernel(
    const float* __restrict__ bits,   // (B, C, P)
    const float* __restrict__ plog,   // (C, M, P)
    const float* __restrict__ vlog,   // (C, M, D)
    float* __restrict__ out)          // (B, C, D)
{
    // bits rows padded to 9 u64 (72 B) to break the 64 B bank stride.
    __shared__ unsigned long long bits_lds[B_N * 9];   // 4.5 KB
    // keys[b][w] padded to 17 u32 per row -> conflict-light scatter write.
    __shared__ unsigned int key_lds[B_N * 17];         // 4.25 KB

    const int c    = blockIdx.x;
    const int tid  = threadIdx.x;
    const int lane = tid & 63;
    const int wid  = tid >> 6;   // 0..15
    const int wm   = wid * 64;   // this wave's first entry index

    // Wave wid owns pattern words [wid*512, +512) = floats [wid*32768, +32768).
    const float* pc = plog + (size_t)c * (M_N * P_N) + (size_t)wid * 32768;

    // ---------------- Phase A: load query rows (this wave's 4 rows) --------
    const int bbase = wid * 4;
    f4 qa0, qa1, qb0, qb1, qc0, qc1, qd0, qd1;
    {
        const f4* s0 = (const f4*)(bits + ((size_t)(bbase + 0) * C_N + c) * P_N);
        const f4* s1 = (const f4*)(bits + ((size_t)(bbase + 1) * C_N + c) * P_N);
        const f4* s2 = (const f4*)(bits + ((size_t)(bbase + 2) * C_N + c) * P_N);
        const f4* s3 = (const f4*)(bits + ((size_t)(bbase + 3) * C_N + c) * P_N);
        qa0 = s0[lane]; qa1 = s0[64 + lane];
        qb0 = s1[lane]; qb1 = s1[64 + lane];
        qc0 = s2[lane]; qc1 = s2[64 + lane];
        qd0 = s3[lane]; qd1 = s3[64 + lane];
    }

    // Pattern pipeline prologue issued now.
    f4 a0, a1, a2, a3, b0, b1, b2, b3, c0, c1, c2, c3, d0, d1, d2, d3;
    PLOAD(a0, a1, a2, a3, 0);
    PLOAD(b0, b1, b2, b3, 1);
    PLOAD(c0, c1, c2, c3, 2);
    PLOAD(d0, d1, d2, d3, 3);

    // ---------------- Phase A ballots: pack query rows into bits_lds -------
    {
        #define QPROC(F0, F1, bb)                                           \
          {                                                                 \
            unsigned long long held = 0, bal;                               \
            bal = __ballot(F0.x > 0.0f); if (lane == 0) held = bal;         \
            bal = __ballot(F0.y > 0.0f); if (lane == 1) held = bal;         \
            bal = __ballot(F0.z > 0.0f); if (lane == 2) held = bal;         \
            bal = __ballot(F0.w > 0.0f); if (lane == 3) held = bal;         \
            bal = __ballot(F1.x > 0.0f); if (lane == 4) held = bal;         \
            bal = __ballot(F1.y > 0.0f); if (lane == 5) held = bal;         \
            bal = __ballot(F1.z > 0.0f); if (lane == 6) held = bal;         \
            bal = __ballot(F1.w > 0.0f); if (lane == 7) held = bal;         \
            if (lane < 8) bits_lds[(bbase + (bb)) * 9 + lane] = held;       \
          }
        QPROC(qa0, qa1, 0);
        QPROC(qb0, qb1, 1);
        QPROC(qc0, qc1, 2);
        QPROC(qd0, qd1, 3);
        #undef QPROC
    }
    __syncthreads();

    // ---------------- Each lane picks up ITS batch row's packed query ------
    const unsigned long long q0 = bits_lds[lane * 9 + 0];
    const unsigned long long q1 = bits_lds[lane * 9 + 1];
    const unsigned long long q2 = bits_lds[lane * 9 + 2];
    const unsigned long long q3 = bits_lds[lane * 9 + 3];
    const unsigned long long q4 = bits_lds[lane * 9 + 4];
    const unsigned long long q5 = bits_lds[lane * 9 + 5];
    const unsigned long long q6 = bits_lds[lane * 9 + 6];
    const unsigned long long q7 = bits_lds[lane * 9 + 7];

    unsigned acc = 0xFFFFFFFFu;

    // ---------------- Main loop: stream + ballot + distance, 4-deep --------
    #pragma unroll 1
    for (int i = 0; i < 28; i += 4) {
        STEP(a0, a1, a2, a3, i,     1);
        STEP(b0, b1, b2, b3, i + 1, 1);
        STEP(c0, c1, c2, c3, i + 2, 1);
        STEP(d0, d1, d2, d3, i + 3, 1);
    }
    STEP(a0, a1, a2, a3, 28, 0);
    STEP(b0, b1, b2, b3, 29, 0);
    STEP(c0, c1, c2, c3, 30, 0);
    STEP(d0, d1, d2, d3, 31, 0);

    // ---------------- Final: cross-wave key reduce + gather ----------------
    key_lds[lane * 17 + wid] = acc;   // [b][w], 17-pad
    __syncthreads();

    {
        const int b = tid >> 4;       // 0..63
        const int g = tid & 15;       // dual role: wave slot, then d index
        unsigned k = key_lds[b * 17 + g];
        k = min(k, __shfl_xor(k, 1));
        k = min(k, __shfl_xor(k, 2));
        k = min(k, __shfl_xor(k, 4));
        k = min(k, __shfl_xor(k, 8));
        const int idx = (int)(k & 1023u);
        const float v = vlog[((size_t)c * M_N + idx) * D_N + g];
        out[((size_t)b * C_N + c) * D_N + g] = (v > 0.0f) ? 1.0f : 0.0f;
    }
}

extern "C" void kernel_launch(void* const* d_in, const int* in_sizes, int n_in,
                              void* d_out, int out_size, void* d_ws, size_t ws_size,
                              hipStream_t stream) {
    const float* bits = (const float*)d_in[0];   // (64, 256, 512)
    const float* plog = (const float*)d_in[1];   // (256, 1024, 512)
    const float* vlog = (const float*)d_in[2];   // (256, 1024, 16)
    float* out = (float*)d_out;                  // (64, 256, 16)

    vgram_kernel<<<C_N, 1024, 0, stream>>>(bits, plog, vlog, out);
}